// Round 10
// baseline (458.917 us; speedup 1.0000x reference)
//
#include <hip/hip_runtime.h>

typedef __attribute__((ext_vector_type(8))) short bf16x8;
typedef __attribute__((ext_vector_type(4))) float f32x4;
typedef __attribute__((ext_vector_type(2))) unsigned u32x2;
typedef __attribute__((ext_vector_type(4))) unsigned u32x4;

#define NBATCH 4
#define NSEQ   2048
#define NDIM   1024
#define NHEAD  16
#define HDIM   64

static __device__ __forceinline__ unsigned short f2bf(float f) {
  unsigned u = __float_as_uint(f);
  u += 0x7fffu + ((u >> 16) & 1u);
  return (unsigned short)(u >> 16);
}

static __device__ __forceinline__ unsigned cvt_pk_bf16(float lo, float hi) {
  unsigned d;
  asm("v_cvt_pk_bf16_f32 %0, %1, %2" : "=v"(d) : "v"(lo), "v"(hi));
  return d;
}

static __device__ __forceinline__ void gload16(const void* g, void* l) {
  __builtin_amdgcn_global_load_lds(
      (const __attribute__((address_space(1))) unsigned*)g,
      (__attribute__((address_space(3))) unsigned*)l, 16, 0, 0);
}

// ---------------- K0: fp32 -> bf16 conversion (hs + 4 weights) ----------------
__global__ __launch_bounds__(256) void cvt_kernel(
    const float* __restrict__ hs, const float* __restrict__ wq,
    const float* __restrict__ wk, const float* __restrict__ wv,
    const float* __restrict__ wo,
    unsigned short* __restrict__ hsb, unsigned short* __restrict__ wqb,
    unsigned short* __restrict__ wkb, unsigned short* __restrict__ wvb,
    unsigned short* __restrict__ wob) {
  long long t = (long long)blockIdx.x * blockDim.x + threadIdx.x;
  long long i4 = t * 4;
  const float* src; unsigned short* dst; long long base;
  if (i4 < 8388608LL) { src = hs; dst = hsb; base = i4; }
  else {
    long long j = i4 - 8388608LL;
    int w = (int)(j >> 20);
    base = j & 1048575LL;
    switch (w) { case 0: src=wq; dst=wqb; break; case 1: src=wk; dst=wkb; break;
                 case 2: src=wv; dst=wvb; break; default: src=wo; dst=wob; break; }
  }
  float4 v = *(const float4*)(src + base);
  unsigned short r0=f2bf(v.x), r1=f2bf(v.y), r2=f2bf(v.z), r3=f2bf(v.w);
  *(uint2*)(dst + base) = make_uint2((unsigned)r0 | ((unsigned)r1<<16),
                                     (unsigned)r2 | ((unsigned)r3<<16));
}

// ---------------- GEMM core: C = A(Mx1024) * W(Nx1024)^T, 128x128 tile ----------------
static __device__ __forceinline__ void gemm128(
    const unsigned short* __restrict__ A, const unsigned short* __restrict__ W,
    unsigned short* As, unsigned short* Bs, int m0, int n0, f32x4 (&acc)[4][4]) {
  const int tid = threadIdx.x;
  const int w = tid >> 6, l = tid & 63, g = l >> 4, r = l & 15;
  const int wm = w >> 1, wn = w & 1;
  const f32x4 z4 = {0.f, 0.f, 0.f, 0.f};
  #pragma unroll
  for (int i = 0; i < 4; ++i)
    #pragma unroll
    for (int j = 0; j < 4; ++j) acc[i][j] = z4;
  const int srow = (l >> 2);          // 0..15 within chunk
  const int scol = (l & 3) * 8;       // 0,8,16,24
  for (int kt = 0; kt < 32; ++kt) {
    const int k0 = kt * 32;
    __syncthreads();
    #pragma unroll
    for (int i = 0; i < 2; ++i) {
      int c8 = w * 2 + i;             // chunk 0..7, 16 rows each
      int row = c8 * 16 + srow;
      gload16(A + (size_t)(m0 + row) * 1024 + k0 + scol, As + c8 * 512);
      gload16(W + (size_t)(n0 + row) * 1024 + k0 + scol, Bs + c8 * 512);
    }
    asm volatile("s_waitcnt vmcnt(0)" ::: "memory");
    __syncthreads();
    bf16x8 af[4], bf[4];
    #pragma unroll
    for (int ma = 0; ma < 4; ++ma)
      af[ma] = *(const bf16x8*)(As + (wm*64 + ma*16 + r) * 32 + g * 8);
    #pragma unroll
    for (int nb = 0; nb < 4; ++nb)
      bf[nb] = *(const bf16x8*)(Bs + (wn*64 + nb*16 + r) * 32 + g * 8);
    #pragma unroll
    for (int ma = 0; ma < 4; ++ma)
      #pragma unroll
      for (int nb = 0; nb < 4; ++nb)
        acc[ma][nb] = __builtin_amdgcn_mfma_f32_16x16x32_bf16(
            af[ma], bf[nb], acc[ma][nb], 0, 0, 0);
  }
}

// ---------------- K1: QKV projections ----------------
// z=0: Q (scaled 1/8) -> [B,NH,S,HD]; z=1: K -> [B,NH,S,HD]; z=2: V -> [B,NH,HD,S]
__global__ __launch_bounds__(256) void qkv_gemm(
    const unsigned short* __restrict__ hsb,
    const unsigned short* __restrict__ wqb, const unsigned short* __restrict__ wkb,
    const unsigned short* __restrict__ wvb,
    const float* __restrict__ bq, const float* __restrict__ bk,
    const float* __restrict__ bv,
    unsigned short* __restrict__ qb, unsigned short* __restrict__ kb,
    unsigned short* __restrict__ vtb) {
  __shared__ unsigned short As[128*32], Bs[128*32];
  const int z = blockIdx.z;
  const unsigned short* W = (z == 0) ? wqb : (z == 1) ? wkb : wvb;
  const float* bias = (z == 0) ? bq : (z == 1) ? bk : bv;
  const int m0 = blockIdx.y * 128, n0 = blockIdx.x * 128;
  f32x4 acc[4][4];
  gemm128(hsb, W, As, Bs, m0, n0, acc);
  const int tid = threadIdx.x, w = tid >> 6, l = tid & 63, g = l >> 4, r = l & 15;
  const int wm = w >> 1, wn = w & 1;
  #pragma unroll
  for (int nb = 0; nb < 4; ++nb) {
    int n = n0 + wn*64 + nb*16 + r;
    float bval = bias[n];
    int h = n >> 6, d = n & 63;
    #pragma unroll
    for (int ma = 0; ma < 4; ++ma) {
      int mbase = m0 + wm*64 + ma*16 + g*4;
      if (z == 2) {
        int b = mbase >> 11, s0 = mbase & 2047;
        unsigned short u[4];
        #pragma unroll
        for (int j = 0; j < 4; ++j) u[j] = f2bf(acc[ma][nb][j] + bval);
        size_t idx = ((size_t)(b*16 + h) * 64 + d) * 2048 + s0;
        *(uint2*)(vtb + idx) = make_uint2((unsigned)u[0] | ((unsigned)u[1]<<16),
                                          (unsigned)u[2] | ((unsigned)u[3]<<16));
      } else {
        unsigned short* dst = (z == 0) ? qb : kb;
        float sc = (z == 0) ? 0.125f : 1.0f;   // fold 1/sqrt(64) into Q (exact pow2)
        #pragma unroll
        for (int j = 0; j < 4; ++j) {
          int m = mbase + j;
          int b = m >> 11, s = m & 2047;
          dst[((size_t)(b*16 + h) * 2048 + s) * 64 + d] = f2bf((acc[ma][nb][j] + bval) * sc);
        }
      }
    }
  }
}

// ---------------- K2: flash attention (LDS-free) ----------------
// Round-10: K/V are L2/L3-resident (512KB/head) -> LDS staging was pure
// overhead (guide mistake #7; m169: +26% from dropping it). K and V^T
// fragments load straight from global into registers (unswizzled address
// map of the verified staged layout). No barriers, no LDS, waves free-run.
// Software pipeline: QK(t) -> reload kf(t+1) under exp phase; vf(t) issued
// after QK, consumed after exp. grid (S/128, B*NH), 4 waves x 32 q-rows.
__global__ __launch_bounds__(256) void flash_attn(
    const unsigned short* __restrict__ qg, const unsigned short* __restrict__ kg,
    const unsigned short* __restrict__ vg, const float* __restrict__ mask,
    unsigned short* __restrict__ ctxb) {
  const int tid = threadIdx.x, w = tid >> 6, l = tid & 63, g = l >> 4, r = l & 15;
  const int bh = blockIdx.y, b = bh >> 4, h = bh & 15;
  const unsigned short* qh = qg + (size_t)bh * 2048 * 64;
  const unsigned short* kh = kg + (size_t)bh * 2048 * 64;
  const unsigned short* vh = vg + (size_t)bh * 64 * 2048;
  const float* maskb = mask + b * 2048;
  const int q0 = blockIdx.x * 128;
  const int wq0 = q0 + w * 32;
  const float L2E = 1.44269504f;
  const float MC  = 14426.950408f;   // 10000 * log2(e)

  // per-lane global bases for direct K / V^T fragment loads
  const unsigned short* kp = kh + (size_t)r * 64 + g * 8;     // + kq*1024 + ks*32 + t*4096
  const unsigned short* vp = vh + (size_t)r * 2048 + g * 8;   // + fn*32768 + ks*32 + k0

  // Q fragments (pre-scaled by 1/8); B-operand of swapped QK^T
  bf16x8 aq[2][2];
  #pragma unroll
  for (int mq = 0; mq < 2; ++mq)
    #pragma unroll
    for (int ks = 0; ks < 2; ++ks)
      aq[mq][ks] = *(const bf16x8*)(qh + (size_t)(wq0 + mq*16 + r) * 64 + ks*32 + g*8);

  const f32x4 z4 = {0.f, 0.f, 0.f, 0.f};
  f32x4 c[2][4];   // ctx^T accumulators: C[d][q], col q = lane&15
  f32x4 cl[2];     // row-sum denominator via ones-A MFMA
  #pragma unroll
  for (int mq = 0; mq < 2; ++mq) {
    #pragma unroll
    for (int fn = 0; fn < 4; ++fn) c[mq][fn] = z4;
    cl[mq] = z4;
  }
  bf16x8 ones;
  #pragma unroll
  for (int i = 0; i < 8; ++i) ones[i] = (short)0x3F80;  // bf16 1.0

  // preload K fragments for tile 0
  bf16x8 kf[4][2];
  #pragma unroll
  for (int kq = 0; kq < 4; ++kq)
    #pragma unroll
    for (int ks = 0; ks < 2; ++ks)
      kf[kq][ks] = *(const bf16x8*)(kp + kq*1024 + ks*32);

  for (int t = 0; t < 32; ++t) {
    const int k0 = t * 64;

    // S^T = mfma(K, Q): C[k][q], col q = lane&15, row k = kq*16 + g*4 + j
    f32x4 sa[2][4];
    #pragma unroll
    for (int mq = 0; mq < 2; ++mq)
      #pragma unroll
      for (int kq = 0; kq < 4; ++kq) sa[mq][kq] = z4;
    __builtin_amdgcn_s_setprio(1);
    #pragma unroll
    for (int kq = 0; kq < 4; ++kq)
      #pragma unroll
      for (int ks = 0; ks < 2; ++ks) {
        sa[0][kq] = __builtin_amdgcn_mfma_f32_16x16x32_bf16(kf[kq][ks], aq[0][ks], sa[0][kq], 0,0,0);
        sa[1][kq] = __builtin_amdgcn_mfma_f32_16x16x32_bf16(kf[kq][ks], aq[1][ks], sa[1][kq], 0,0,0);
      }
    __builtin_amdgcn_s_setprio(0);

    // V fragments for this tile (consumed after exp -> latency hidden)
    bf16x8 vf[4][2];
    #pragma unroll
    for (int fn = 0; fn < 4; ++fn)
      #pragma unroll
      for (int ks = 0; ks < 2; ++ks)
        vf[fn][ks] = *(const bf16x8*)(vp + fn*32768 + k0 + ks*32);

    // K fragments for next tile (kf regs free after QK; land under exp+PV)
    if (t < 31) {
      #pragma unroll
      for (int kq = 0; kq < 4; ++kq)
        #pragma unroll
        for (int ks = 0; ks < 2; ++ks)
          kf[kq][ks] = *(const bf16x8*)(kp + (t+1)*4096 + kq*1024 + ks*32);
    }

    // mask terms: lane's keys are kq*16 + g*4 + j
    float md[16];
    #pragma unroll
    for (int kq = 0; kq < 4; ++kq) {
      float4 m4 = *(const float4*)(maskb + k0 + kq*16 + g*4);
      md[kq*4+0] = fmaf(m4.x, MC, -MC);
      md[kq*4+1] = fmaf(m4.y, MC, -MC);
      md[kq*4+2] = fmaf(m4.z, MC, -MC);
      md[kq*4+3] = fmaf(m4.w, MC, -MC);
    }

    // P = exp(s + madd) -> bf16 pairs -> permlane network -> PV B-fragments
    bf16x8 pb[2][2];
    #pragma unroll
    for (int mq = 0; mq < 2; ++mq) {
      unsigned pk[4][2];
      #pragma unroll
      for (int kq = 0; kq < 4; ++kq) {
        float p0 = exp2f(fmaf(sa[mq][kq][0], L2E, md[kq*4+0]));
        float p1 = exp2f(fmaf(sa[mq][kq][1], L2E, md[kq*4+1]));
        float p2 = exp2f(fmaf(sa[mq][kq][2], L2E, md[kq*4+2]));
        float p3 = exp2f(fmaf(sa[mq][kq][3], L2E, md[kq*4+3]));
        pk[kq][0] = cvt_pk_bf16(p0, p1);
        pk[kq][1] = cvt_pk_bf16(p2, p3);
      }
      #pragma unroll
      for (int ch = 0; ch < 2; ++ch) {
        u32x4 fr;
        #pragma unroll
        for (int i = 0; i < 2; ++i) {
          u32x2 s1 = __builtin_amdgcn_permlane32_swap(pk[ch*2][i], pk[ch*2+1][i], false, false);
          u32x2 s2 = __builtin_amdgcn_permlane16_swap(s1.x, s1.y, false, false);
          fr[i]     = s2.x;   // keys g*8 + {2i, 2i+1}
          fr[2 + i] = s2.y;   // keys g*8 + 4 + {2i, 2i+1}
        }
        pb[mq][ch] = __builtin_bit_cast(bf16x8, fr);
      }
    }

    // ctx^T += mfma(V^T-frag, P^T-frag); denominator += mfma(ones, P^T-frag)
    __builtin_amdgcn_s_setprio(1);
    #pragma unroll
    for (int ks = 0; ks < 2; ++ks) {
      #pragma unroll
      for (int fn = 0; fn < 4; ++fn) {
        c[0][fn] = __builtin_amdgcn_mfma_f32_16x16x32_bf16(vf[fn][ks], pb[0][ks], c[0][fn], 0,0,0);
        c[1][fn] = __builtin_amdgcn_mfma_f32_16x16x32_bf16(vf[fn][ks], pb[1][ks], c[1][fn], 0,0,0);
      }
      cl[0] = __builtin_amdgcn_mfma_f32_16x16x32_bf16(ones, pb[0][ks], cl[0], 0,0,0);
      cl[1] = __builtin_amdgcn_mfma_f32_16x16x32_bf16(ones, pb[1][ks], cl[1], 0,0,0);
    }
    __builtin_amdgcn_s_setprio(0);
  }

  // normalize + write ctx (bf16, [B,S,D]); lane's q = r, d = fn*16 + g*4 + j
  #pragma unroll
  for (int mq = 0; mq < 2; ++mq) {
    float inv = 1.0f / cl[mq][0];
    int srow = q0 + w*32 + mq*16 + r;
    size_t base = ((size_t)(b * 2048 + srow)) * 1024 + h * 64;
    #pragma unroll
    for (int fn = 0; fn < 4; ++fn) {
      unsigned short u0 = f2bf(c[mq][fn][0] * inv);
      unsigned short u1 = f2bf(c[mq][fn][1] * inv);
      unsigned short u2 = f2bf(c[mq][fn][2] * inv);
      unsigned short u3 = f2bf(c[mq][fn][3] * inv);
      *(uint2*)(ctxb + base + fn*16 + g*4) =
          make_uint2((unsigned)u0 | ((unsigned)u1<<16),
                     (unsigned)u2 | ((unsigned)u3<<16));
    }
  }
}

// ---------------- K3: output projection (fp32 out + bias) ----------------
__global__ __launch_bounds__(256) void out_gemm(
    const unsigned short* __restrict__ ctxb, const unsigned short* __restrict__ wob,
    const float* __restrict__ bo, float* __restrict__ out) {
  __shared__ unsigned short As[128*32], Bs[128*32];
  const int m0 = blockIdx.y * 128, n0 = blockIdx.x * 128;
  f32x4 acc[4][4];
  gemm128(ctxb, wob, As, Bs, m0, n0, acc);
  const int tid = threadIdx.x, w = tid >> 6, l = tid & 63, g = l >> 4, r = l & 15;
  const int wm = w >> 1, wn = w & 1;
  #pragma unroll
  for (int nb = 0; nb < 4; ++nb) {
    int n = n0 + wn*64 + nb*16 + r;
    float bval = bo[n];
    #pragma unroll
    for (int ma = 0; ma < 4; ++ma)
      #pragma unroll
      for (int j = 0; j < 4; ++j) {
        int m = m0 + wm*64 + ma*16 + g*4 + j;
        out[(size_t)m * 1024 + n] = acc[ma][nb][j] + bval;
      }
  }
}

extern "C" void kernel_launch(void* const* d_in, const int* in_sizes, int n_in,
                              void* d_out, int out_size, void* d_ws, size_t ws_size,
                              hipStream_t stream) {
  const float* hs   = (const float*)d_in[0];
  const float* mask = (const float*)d_in[1];
  const float* wq   = (const float*)d_in[2];
  const float* bq   = (const float*)d_in[3];
  const float* wk   = (const float*)d_in[4];
  const float* bk   = (const float*)d_in[5];
  const float* wv   = (const float*)d_in[6];
  const float* bv   = (const float*)d_in[7];
  const float* wo   = (const float*)d_in[8];
  const float* bo   = (const float*)d_in[9];
  float* out = (float*)d_out;
  char* ws = (char*)d_ws;
  unsigned short* hsb = (unsigned short*)(ws);                      // 16 MB
  unsigned short* wqb = (unsigned short*)(ws + (16ull << 20));      //  2 MB
  unsigned short* wkb = (unsigned short*)(ws + (18ull << 20));
  unsigned short* wvb = (unsigned short*)(ws + (20ull << 20));
  unsigned short* wob = (unsigned short*)(ws + (22ull << 20));
  unsigned short* qb  = (unsigned short*)(ws + (24ull << 20));      // 16 MB [B,NH,S,HD]
  unsigned short* kb  = (unsigned short*)(ws + (40ull << 20));      // 16 MB [B,NH,S,HD]
  unsigned short* vtb = (unsigned short*)(ws + (56ull << 20));      // 16 MB [B,NH,HD,S]
  unsigned short* ctb = (unsigned short*)(ws + (72ull << 20));      // 16 MB [M,D]

  cvt_kernel<<<12288, 256, 0, stream>>>(hs, wq, wk, wv, wo, hsb, wqb, wkb, wvb, wob);
  qkv_gemm<<<dim3(8, 64, 3), 256, 0, stream>>>(hsb, wqb, wkb, wvb, bq, bk, bv, qb, kb, vtb);
  flash_attn<<<dim3(16, 64), 256, 0, stream>>>(qb, kb, vtb, mask, ctb);
  out_gemm<<<dim3(8, 64), 256, 0, stream>>>(ctb, wob, bo, out);
}

// Round 11
// 335.810 us; speedup vs baseline: 1.3666x; 1.3666x over previous
//
#include <hip/hip_runtime.h>

typedef __attribute__((ext_vector_type(8))) short bf16x8;
typedef __attribute__((ext_vector_type(4))) float f32x4;
typedef __attribute__((ext_vector_type(2))) unsigned u32x2;
typedef __attribute__((ext_vector_type(4))) unsigned u32x4;

#define NBATCH 4
#define NSEQ   2048
#define NDIM   1024
#define NHEAD  16
#define HDIM   64

static __device__ __forceinline__ unsigned short f2bf(float f) {
  unsigned u = __float_as_uint(f);
  u += 0x7fffu + ((u >> 16) & 1u);
  return (unsigned short)(u >> 16);
}

static __device__ __forceinline__ unsigned cvt_pk_bf16(float lo, float hi) {
  unsigned d;
  asm("v_cvt_pk_bf16_f32 %0, %1, %2" : "=v"(d) : "v"(lo), "v"(hi));
  return d;
}

// raw v_exp_f32 (D = 2^S0) — bypasses OCML's multi-instruction exp2f guard
// sequence; our args are bounded (<= ~6), underflow-to-0 is native HW behavior.
static __device__ __forceinline__ float exp2_raw(float x) {
  float d;
  asm("v_exp_f32 %0, %1" : "=v"(d) : "v"(x));
  return d;
}

static __device__ __forceinline__ void gload16(const void* g, void* l) {
  __builtin_amdgcn_global_load_lds(
      (const __attribute__((address_space(1))) unsigned*)g,
      (__attribute__((address_space(3))) unsigned*)l, 16, 0, 0);
}

// ---------------- K0: fp32 -> bf16 conversion (hs + 4 weights) ----------------
__global__ __launch_bounds__(256) void cvt_kernel(
    const float* __restrict__ hs, const float* __restrict__ wq,
    const float* __restrict__ wk, const float* __restrict__ wv,
    const float* __restrict__ wo,
    unsigned short* __restrict__ hsb, unsigned short* __restrict__ wqb,
    unsigned short* __restrict__ wkb, unsigned short* __restrict__ wvb,
    unsigned short* __restrict__ wob) {
  long long t = (long long)blockIdx.x * blockDim.x + threadIdx.x;
  long long i4 = t * 4;
  const float* src; unsigned short* dst; long long base;
  if (i4 < 8388608LL) { src = hs; dst = hsb; base = i4; }
  else {
    long long j = i4 - 8388608LL;
    int w = (int)(j >> 20);
    base = j & 1048575LL;
    switch (w) { case 0: src=wq; dst=wqb; break; case 1: src=wk; dst=wkb; break;
                 case 2: src=wv; dst=wvb; break; default: src=wo; dst=wob; break; }
  }
  float4 v = *(const float4*)(src + base);
  unsigned short r0=f2bf(v.x), r1=f2bf(v.y), r2=f2bf(v.z), r3=f2bf(v.w);
  *(uint2*)(dst + base) = make_uint2((unsigned)r0 | ((unsigned)r1<<16),
                                     (unsigned)r2 | ((unsigned)r3<<16));
}

// ---------------- GEMM core: C = A(Mx1024) * W(Nx1024)^T, 128x128 tile ----------------
static __device__ __forceinline__ void gemm128(
    const unsigned short* __restrict__ A, const unsigned short* __restrict__ W,
    unsigned short* As, unsigned short* Bs, int m0, int n0, f32x4 (&acc)[4][4]) {
  const int tid = threadIdx.x;
  const int w = tid >> 6, l = tid & 63, g = l >> 4, r = l & 15;
  const int wm = w >> 1, wn = w & 1;
  const f32x4 z4 = {0.f, 0.f, 0.f, 0.f};
  #pragma unroll
  for (int i = 0; i < 4; ++i)
    #pragma unroll
    for (int j = 0; j < 4; ++j) acc[i][j] = z4;
  const int srow = (l >> 2);          // 0..15 within chunk
  const int scol = (l & 3) * 8;       // 0,8,16,24
  for (int kt = 0; kt < 32; ++kt) {
    const int k0 = kt * 32;
    __syncthreads();
    #pragma unroll
    for (int i = 0; i < 2; ++i) {
      int c8 = w * 2 + i;             // chunk 0..7, 16 rows each
      int row = c8 * 16 + srow;
      gload16(A + (size_t)(m0 + row) * 1024 + k0 + scol, As + c8 * 512);
      gload16(W + (size_t)(n0 + row) * 1024 + k0 + scol, Bs + c8 * 512);
    }
    asm volatile("s_waitcnt vmcnt(0)" ::: "memory");
    __syncthreads();
    bf16x8 af[4], bf[4];
    #pragma unroll
    for (int ma = 0; ma < 4; ++ma)
      af[ma] = *(const bf16x8*)(As + (wm*64 + ma*16 + r) * 32 + g * 8);
    #pragma unroll
    for (int nb = 0; nb < 4; ++nb)
      bf[nb] = *(const bf16x8*)(Bs + (wn*64 + nb*16 + r) * 32 + g * 8);
    #pragma unroll
    for (int ma = 0; ma < 4; ++ma)
      #pragma unroll
      for (int nb = 0; nb < 4; ++nb)
        acc[ma][nb] = __builtin_amdgcn_mfma_f32_16x16x32_bf16(
            af[ma], bf[nb], acc[ma][nb], 0, 0, 0);
  }
}

// ---------------- K1: QKV projections ----------------
// z=0: Q (scaled 1/8) -> [B,NH,S,HD]; z=1: K -> [B,NH,S,HD]; z=2: V -> [B,NH,HD,S]
__global__ __launch_bounds__(256) void qkv_gemm(
    const unsigned short* __restrict__ hsb,
    const unsigned short* __restrict__ wqb, const unsigned short* __restrict__ wkb,
    const unsigned short* __restrict__ wvb,
    const float* __restrict__ bq, const float* __restrict__ bk,
    const float* __restrict__ bv,
    unsigned short* __restrict__ qb, unsigned short* __restrict__ kb,
    unsigned short* __restrict__ vtb) {
  __shared__ unsigned short As[128*32], Bs[128*32];
  const int z = blockIdx.z;
  const unsigned short* W = (z == 0) ? wqb : (z == 1) ? wkb : wvb;
  const float* bias = (z == 0) ? bq : (z == 1) ? bk : bv;
  const int m0 = blockIdx.y * 128, n0 = blockIdx.x * 128;
  f32x4 acc[4][4];
  gemm128(hsb, W, As, Bs, m0, n0, acc);
  const int tid = threadIdx.x, w = tid >> 6, l = tid & 63, g = l >> 4, r = l & 15;
  const int wm = w >> 1, wn = w & 1;
  #pragma unroll
  for (int nb = 0; nb < 4; ++nb) {
    int n = n0 + wn*64 + nb*16 + r;
    float bval = bias[n];
    int h = n >> 6, d = n & 63;
    #pragma unroll
    for (int ma = 0; ma < 4; ++ma) {
      int mbase = m0 + wm*64 + ma*16 + g*4;
      if (z == 2) {
        int b = mbase >> 11, s0 = mbase & 2047;
        unsigned short u[4];
        #pragma unroll
        for (int j = 0; j < 4; ++j) u[j] = f2bf(acc[ma][nb][j] + bval);
        size_t idx = ((size_t)(b*16 + h) * 64 + d) * 2048 + s0;
        *(uint2*)(vtb + idx) = make_uint2((unsigned)u[0] | ((unsigned)u[1]<<16),
                                          (unsigned)u[2] | ((unsigned)u[3]<<16));
      } else {
        unsigned short* dst = (z == 0) ? qb : kb;
        float sc = (z == 0) ? 0.125f : 1.0f;   // fold 1/sqrt(64) into Q (exact pow2)
        #pragma unroll
        for (int j = 0; j < 4; ++j) {
          int m = mbase + j;
          int b = m >> 11, s = m & 2047;
          dst[((size_t)(b*16 + h) * 2048 + s) * 64 + d] = f2bf((acc[ma][nb][j] + bval) * sc);
        }
      }
    }
  }
}

// ---------------- K2: flash attention ----------------
// Round-7 structure (best measured: 151 us) with ONE change: exp2f -> raw
// v_exp_f32 (round-11 theory: OCML exp2f multi-instr guard was the VALU
// consumer; issue port was ~88% saturated MFMA+VALU).
__global__ __launch_bounds__(256) void flash_attn(
    const unsigned short* __restrict__ qg, const unsigned short* __restrict__ kg,
    const unsigned short* __restrict__ vg, const float* __restrict__ mask,
    unsigned short* __restrict__ ctxb) {
  __shared__ unsigned short Kl[2][4096], Vl[2][4096];
  const int tid = threadIdx.x, w = tid >> 6, l = tid & 63, g = l >> 4, r = l & 15;
  const int bh = blockIdx.y, b = bh >> 4, h = bh & 15;
  const unsigned short* qh = qg + (size_t)bh * 2048 * 64;
  const unsigned short* kh = kg + (size_t)bh * 2048 * 64;
  const unsigned short* vh = vg + (size_t)bh * 64 * 2048;
  const float* maskb = mask + b * 2048;
  const int q0 = blockIdx.x * 128;
  const int wq0 = q0 + w * 32;
  const float L2E = 1.44269504f;
  const float MC  = 14426.950408f;   // 10000 * log2(e)

  // Q fragments (pre-scaled by 1/8); B-operand of swapped QK^T
  bf16x8 aq[2][2];
  #pragma unroll
  for (int mq = 0; mq < 2; ++mq)
    #pragma unroll
    for (int ks = 0; ks < 2; ++ks)
      aq[mq][ks] = *(const bf16x8*)(qh + (size_t)(wq0 + mq*16 + r) * 64 + ks*32 + g*8);

  const f32x4 z4 = {0.f, 0.f, 0.f, 0.f};
  f32x4 c[2][4];   // ctx^T accumulators: C[d][q], col q = lane&15
  f32x4 cl[2];     // row-sum denominator via ones-A MFMA
  #pragma unroll
  for (int mq = 0; mq < 2; ++mq) {
    #pragma unroll
    for (int fn = 0; fn < 4; ++fn) c[mq][fn] = z4;
    cl[mq] = z4;
  }
  bf16x8 ones;
  #pragma unroll
  for (int i = 0; i < 8; ++i) ones[i] = (short)0x3F80;  // bf16 1.0

  const int strow = l >> 3;
  const int stsl  = l & 7;

  // prologue: stage tile 0
  #pragma unroll
  for (int i = 0; i < 2; ++i) {
    int c8 = w * 2 + i;
    int row = c8 * 8 + strow;
    int sl = stsl ^ (row & 7);
    gload16(kh + (size_t)row * 64 + sl * 8, &Kl[0][c8 * 512]);
    gload16(vh + (size_t)row * 2048 + sl * 8, &Vl[0][c8 * 512]);
  }
  asm volatile("s_waitcnt vmcnt(0)" ::: "memory");
  __syncthreads();

  for (int kt = 0; kt < 32; ++kt) {
    const int cur = kt & 1;
    const int k0 = kt * 64;
    const unsigned short* Kc = Kl[cur];
    const unsigned short* Vc = Vl[cur];

    // async prefetch next K/V tile
    if (kt < 31) {
      unsigned short* Kn = Kl[cur ^ 1];
      unsigned short* Vn = Vl[cur ^ 1];
      #pragma unroll
      for (int i = 0; i < 2; ++i) {
        int c8 = w * 2 + i;
        int row = c8 * 8 + strow;
        int sl = stsl ^ (row & 7);
        gload16(kh + (size_t)(k0 + 64 + row) * 64 + sl * 8, Kn + c8 * 512);
        gload16(vh + (size_t)row * 2048 + k0 + 64 + sl * 8, Vn + c8 * 512);
      }
    }

    // mask terms: lane's keys are kq*16 + g*4 + j  (consecutive j -> float4)
    float md[16];
    #pragma unroll
    for (int kq = 0; kq < 4; ++kq) {
      float4 m4 = *(const float4*)(maskb + k0 + kq*16 + g*4);
      md[kq*4+0] = fmaf(m4.x, MC, -MC);
      md[kq*4+1] = fmaf(m4.y, MC, -MC);
      md[kq*4+2] = fmaf(m4.z, MC, -MC);
      md[kq*4+3] = fmaf(m4.w, MC, -MC);
    }

    // S^T = mfma(K, Q): C[k][q], col q = lane&15, row k = kq*16 + g*4 + j
    f32x4 sa[2][4];
    #pragma unroll
    for (int mq = 0; mq < 2; ++mq)
      #pragma unroll
      for (int kq = 0; kq < 4; ++kq) sa[mq][kq] = z4;
    __builtin_amdgcn_s_setprio(1);
    #pragma unroll
    for (int kq = 0; kq < 4; ++kq) {
      int key = kq*16 + r;
      #pragma unroll
      for (int ks = 0; ks < 2; ++ks) {
        bf16x8 kf = *(const bf16x8*)(Kc + key*64 + (((ks*4 + g) ^ (key & 7)) * 8));
        sa[0][kq] = __builtin_amdgcn_mfma_f32_16x16x32_bf16(kf, aq[0][ks], sa[0][kq], 0,0,0);
        sa[1][kq] = __builtin_amdgcn_mfma_f32_16x16x32_bf16(kf, aq[1][ks], sa[1][kq], 0,0,0);
      }
    }
    __builtin_amdgcn_s_setprio(0);

    // P = 2^(s*log2e + md) via raw v_exp_f32 -> bf16 pairs -> permlane network
    bf16x8 pb[2][2];
    #pragma unroll
    for (int mq = 0; mq < 2; ++mq) {
      unsigned pk[4][2];
      #pragma unroll
      for (int kq = 0; kq < 4; ++kq) {
        float p0 = exp2_raw(fmaf(sa[mq][kq][0], L2E, md[kq*4+0]));
        float p1 = exp2_raw(fmaf(sa[mq][kq][1], L2E, md[kq*4+1]));
        float p2 = exp2_raw(fmaf(sa[mq][kq][2], L2E, md[kq*4+2]));
        float p3 = exp2_raw(fmaf(sa[mq][kq][3], L2E, md[kq*4+3]));
        pk[kq][0] = cvt_pk_bf16(p0, p1);
        pk[kq][1] = cvt_pk_bf16(p2, p3);
      }
      #pragma unroll
      for (int ch = 0; ch < 2; ++ch) {
        u32x4 fr;
        #pragma unroll
        for (int i = 0; i < 2; ++i) {
          u32x2 s1 = __builtin_amdgcn_permlane32_swap(pk[ch*2][i], pk[ch*2+1][i], false, false);
          u32x2 s2 = __builtin_amdgcn_permlane16_swap(s1.x, s1.y, false, false);
          fr[i]     = s2.x;   // keys g*8 + {2i, 2i+1}
          fr[2 + i] = s2.y;   // keys g*8 + 4 + {2i, 2i+1}
        }
        pb[mq][ch] = __builtin_bit_cast(bf16x8, fr);
      }
    }

    // ctx^T += mfma(V^T-frag, P^T-frag); denominator += mfma(ones, P^T-frag)
    __builtin_amdgcn_s_setprio(1);
    #pragma unroll
    for (int ks = 0; ks < 2; ++ks) {
      #pragma unroll
      for (int fn = 0; fn < 4; ++fn) {
        int vrow = fn*16 + r;
        bf16x8 vf = *(const bf16x8*)(Vc + vrow*64 + (((ks*4 + g) ^ (vrow & 7)) * 8));
        c[0][fn] = __builtin_amdgcn_mfma_f32_16x16x32_bf16(vf, pb[0][ks], c[0][fn], 0,0,0);
        c[1][fn] = __builtin_amdgcn_mfma_f32_16x16x32_bf16(vf, pb[1][ks], c[1][fn], 0,0,0);
      }
      cl[0] = __builtin_amdgcn_mfma_f32_16x16x32_bf16(ones, pb[0][ks], cl[0], 0,0,0);
      cl[1] = __builtin_amdgcn_mfma_f32_16x16x32_bf16(ones, pb[1][ks], cl[1], 0,0,0);
    }
    __builtin_amdgcn_s_setprio(0);

    // drain prefetch, release buffers
    asm volatile("s_waitcnt vmcnt(0)" ::: "memory");
    __syncthreads();
  }

  // normalize + write ctx (bf16, [B,S,D]); lane's q = r, d = fn*16 + g*4 + j
  #pragma unroll
  for (int mq = 0; mq < 2; ++mq) {
    float inv = 1.0f / cl[mq][0];
    int srow = q0 + w*32 + mq*16 + r;
    size_t base = ((size_t)(b * 2048 + srow)) * 1024 + h * 64;
    #pragma unroll
    for (int fn = 0; fn < 4; ++fn) {
      unsigned short u0 = f2bf(c[mq][fn][0] * inv);
      unsigned short u1 = f2bf(c[mq][fn][1] * inv);
      unsigned short u2 = f2bf(c[mq][fn][2] * inv);
      unsigned short u3 = f2bf(c[mq][fn][3] * inv);
      *(uint2*)(ctxb + base + fn*16 + g*4) =
          make_uint2((unsigned)u0 | ((unsigned)u1<<16),
                     (unsigned)u2 | ((unsigned)u3<<16));
    }
  }
}

// ---------------- K3: output projection (fp32 out + bias) ----------------
__global__ __launch_bounds__(256) void out_gemm(
    const unsigned short* __restrict__ ctxb, const unsigned short* __restrict__ wob,
    const float* __restrict__ bo, float* __restrict__ out) {
  __shared__ unsigned short As[128*32], Bs[128*32];
  const int m0 = blockIdx.y * 128, n0 = blockIdx.x * 128;
  f32x4 acc[4][4];
  gemm128(ctxb, wob, As, Bs, m0, n0, acc);
  const int tid = threadIdx.x, w = tid >> 6, l = tid & 63, g = l >> 4, r = l & 15;
  const int wm = w >> 1, wn = w & 1;
  #pragma unroll
  for (int nb = 0; nb < 4; ++nb) {
    int n = n0 + wn*64 + nb*16 + r;
    float bval = bo[n];
    #pragma unroll
    for (int ma = 0; ma < 4; ++ma)
      #pragma unroll
      for (int j = 0; j < 4; ++j) {
        int m = m0 + wm*64 + ma*16 + g*4 + j;
        out[(size_t)m * 1024 + n] = acc[ma][nb][j] + bval;
      }
  }
}

extern "C" void kernel_launch(void* const* d_in, const int* in_sizes, int n_in,
                              void* d_out, int out_size, void* d_ws, size_t ws_size,
                              hipStream_t stream) {
  const float* hs   = (const float*)d_in[0];
  const float* mask = (const float*)d_in[1];
  const float* wq   = (const float*)d_in[2];
  const float* bq   = (const float*)d_in[3];
  const float* wk   = (const float*)d_in[4];
  const float* bk   = (const float*)d_in[5];
  const float* wv   = (const float*)d_in[6];
  const float* bv   = (const float*)d_in[7];
  const float* wo   = (const float*)d_in[8];
  const float* bo   = (const float*)d_in[9];
  float* out = (float*)d_out;
  char* ws = (char*)d_ws;
  unsigned short* hsb = (unsigned short*)(ws);                      // 16 MB
  unsigned short* wqb = (unsigned short*)(ws + (16ull << 20));      //  2 MB
  unsigned short* wkb = (unsigned short*)(ws + (18ull << 20));
  unsigned short* wvb = (unsigned short*)(ws + (20ull << 20));
  unsigned short* wob = (unsigned short*)(ws + (22ull << 20));
  unsigned short* qb  = (unsigned short*)(ws + (24ull << 20));      // 16 MB [B,NH,S,HD]
  unsigned short* kb  = (unsigned short*)(ws + (40ull << 20));      // 16 MB [B,NH,S,HD]
  unsigned short* vtb = (unsigned short*)(ws + (56ull << 20));      // 16 MB [B,NH,HD,S]
  unsigned short* ctb = (unsigned short*)(ws + (72ull << 20));      // 16 MB [M,D]

  cvt_kernel<<<12288, 256, 0, stream>>>(hs, wq, wk, wv, wo, hsb, wqb, wkb, wvb, wob);
  qkv_gemm<<<dim3(8, 64, 3), 256, 0, stream>>>(hsb, wqb, wkb, wvb, bq, bk, bv, qb, kb, vtb);
  flash_attn<<<dim3(16, 64), 256, 0, stream>>>(qb, kb, vtb, mask, ctb);
  out_gemm<<<dim3(8, 64), 256, 0, stream>>>(ctb, wob, bo, out);
}